// Round 3
// baseline (409.613 us; speedup 1.0000x reference)
//
#include <hip/hip_runtime.h>
#include <math.h>

#define BATCH 2
#define NCH 21
#define CPAD 24            // channels padded to 24 (48 B fp16 / 96 B fp32 per pixel)
#define HH 512
#define WW 512
#define KS 5
#define RAD 2
#define NTAPS 25
#define NPAIR 13           // 25 taps packed as 13 half2 pairs (last hi = 0)
#define NUM_ITERS 10

// iteration-kernel tile
#define TX 32
#define TY 8
#define HX (TX + 2*RAD)    // 36
#define HY (TY + 2*RAD)    // 12
#define HPX (HX * HY)      // 432 halo pixels

typedef _Float16 f16;
typedef _Float16 half8 __attribute__((ext_vector_type(8)));
typedef _Float16 half2v __attribute__((ext_vector_type(2)));

__device__ __forceinline__ int refl(int i, int n) {
    if (i < 0) i = -i;
    if (i >= n) i = 2*n - 2 - i;
    return i;
}

// ---------------- Kernel A: combined normalized weights, half2 tap-pairs ----------------
// w[tap] = G2d_norm[tap] + w_rgb[tap]/sum(w_rgb) + w_edge[tap]/sum(w_edge)
// layout: wc2[b][pair][y][x] = half2(w[2*pair], w[2*pair+1]), w[25]=0
__global__ void weights_kernel(const float* __restrict__ image,
                               const float* __restrict__ edges,
                               half2v* __restrict__ wc2) {
    int idx = blockIdx.x * blockDim.x + threadIdx.x;
    if (idx >= BATCH * HH * WW) return;
    int x = idx % WW;
    int y = (idx / WW) % HH;
    int b = idx / (HH * WW);

    float gs[3];
    gs[0] = 1.0f; gs[1] = expf(-1.0f / 50.0f); gs[2] = expf(-4.0f / 50.0f);
    float gb[3];
    gb[0] = 1.0f; gb[1] = expf(-2.0f); gb[2] = expf(-8.0f);
    float gbs = gb[0] + 2.0f * (gb[1] + gb[2]);
    gb[0] /= gbs; gb[1] /= gbs; gb[2] /= gbs;

    const size_t plane = (size_t)HH * WW;
    const float* img = image + (size_t)b * 3 * plane;
    const float* edg = edges + (size_t)b * plane;

    float r0 = img[0 * plane + y * WW + x];
    float r1 = img[1 * plane + y * WW + x];
    float r2 = img[2 * plane + y * WW + x];
    float e0 = edg[y * WW + x];

    float wr[NTAPS], we[NTAPS];
    float sr = 0.f, se = 0.f;
#pragma unroll
    for (int dy = 0; dy < KS; dy++) {
        int yy = refl(y + dy - RAD, HH);
#pragma unroll
        for (int dx = 0; dx < KS; dx++) {
            int xx = refl(x + dx - RAD, WW);
            float sp = gs[abs(dy - RAD)] * gs[abs(dx - RAD)];
            float d = fabsf(img[0 * plane + yy * WW + xx] - r0)
                    + fabsf(img[1 * plane + yy * WW + xx] - r1)
                    + fabsf(img[2 * plane + yy * WW + xx] - r2);
            float w1 = sp * expf(-2.0f * d * d);
            float de = fabsf(edg[yy * WW + xx] - e0);
            float w2 = sp * expf(-2.0f * de * de);
            wr[dy * KS + dx] = w1;
            we[dy * KS + dx] = w2;
            sr += w1;
            se += w2;
        }
    }
    float isr = 1.0f / sr, ise = 1.0f / se;
    float wt[NTAPS + 1];
#pragma unroll
    for (int t = 0; t < NTAPS; t++) {
        int dy = t / KS, dx = t % KS;
        float g2 = gb[abs(dy - RAD)] * gb[abs(dx - RAD)];
        wt[t] = g2 + wr[t] * isr + we[t] * ise;
    }
    wt[NTAPS] = 0.f;
#pragma unroll
    for (int p = 0; p < NPAIR; p++) {
        half2v h;
        h[0] = (f16)wt[2 * p];
        h[1] = (f16)wt[2 * p + 1];
        wc2[((size_t)b * NPAIR + p) * plane + (size_t)y * WW + x] = h;
    }
}

// ---------------- Kernel B: initial softmax -> interleaved fp16 q + interleaved fp32 unary ----------------
__global__ void init_kernel(const float* __restrict__ unary,
                            f16* __restrict__ q,
                            float* __restrict__ uint_) {
    int idx = blockIdx.x * blockDim.x + threadIdx.x;
    if (idx >= BATCH * HH * WW) return;
    int p = idx % (HH * WW);
    int b = idx / (HH * WW);
    const size_t plane = (size_t)HH * WW;
    const float* u = unary + (size_t)b * NCH * plane + p;
    float l[CPAD];
    float m = -1e30f;
#pragma unroll
    for (int c = 0; c < NCH; c++) { l[c] = u[c * plane]; m = fmaxf(m, l[c]); }
    l[21] = 0.f; l[22] = 0.f; l[23] = 0.f;

    // interleaved fp32 unary
    float4* uo = (float4*)(uint_ + ((size_t)b * plane + p) * CPAD);
#pragma unroll
    for (int g = 0; g < 6; g++)
        uo[g] = make_float4(l[g * 4 + 0], l[g * 4 + 1], l[g * 4 + 2], l[g * 4 + 3]);

    float s = 0.f;
    float e[CPAD];
#pragma unroll
    for (int c = 0; c < NCH; c++) { e[c] = expf(l[c] - m); s += e[c]; }
    float is = 1.0f / s;
    e[21] = 0.f; e[22] = 0.f; e[23] = 0.f;
    half8* qo = (half8*)(q + ((size_t)b * plane + p) * CPAD);
#pragma unroll
    for (int g = 0; g < 3; g++) {
        half8 v;
#pragma unroll
        for (int k = 0; k < 8; k++) v[k] = (f16)(e[g * 8 + k] * is);
        qo[g] = v;
    }
}

// ---------------- Kernel C: one fused CRF iteration ----------------
// new_q = softmax(unary - f),  f_c = sum_tap w[tap] * q[c][nbr(tap)]
template <bool FINAL>
__global__ __launch_bounds__(256, 4) void crf_iter_kernel(const f16* __restrict__ qin,
                                                          const float* __restrict__ uint_,
                                                          const half2v* __restrict__ wc2,
                                                          void* __restrict__ qout) {
    // fp16 halo tile, interleaved: tileH[px][24 halfs] = 48 B/px, 20736 B total
    __shared__ __align__(16) f16 tileH[HPX][CPAD];

    const int tx = threadIdx.x;      // 0..31
    const int ty = threadIdx.y;      // 0..7
    const int tid = ty * TX + tx;
    const int x0 = blockIdx.x * TX;
    const int y0 = blockIdx.y * TY;
    const int b = blockIdx.z;
    const int x = x0 + tx;
    const int y = y0 + ty;
    const size_t plane = (size_t)HH * WW;

    // ---- stage 12x36 halo, fp16 global -> fp16 LDS, no conversion ----
    const f16* qb = qin + (size_t)b * plane * CPAD;
    for (int idx = tid; idx < HPX * 3; idx += TX * TY) {
        int px = idx / 3, h4 = idx - px * 3;        // h4-fastest: contiguous 16B global chunks
        int ly = px / HX, lx = px - ly * HX;
        int gy = refl(y0 + ly - RAD, HH);
        int gx = refl(x0 + lx - RAD, WW);
        half8 v = *(const half8*)(qb + ((size_t)gy * WW + gx) * CPAD + h4 * 8);
        *(half8*)&tileH[px][h4 * 8] = v;
    }

    // per-pixel combined weights, half2 pairs -> fp32 registers
    float wcr[NTAPS + 1];
    {
        const half2v* wp = wc2 + (size_t)b * NPAIR * plane + (size_t)y * WW + x;
#pragma unroll
        for (int p = 0; p < NPAIR; p++) {
            half2v h = wp[p * plane];
            wcr[2 * p] = (float)h[0];
            wcr[2 * p + 1] = (float)h[1];
        }
    }

    __syncthreads();

    // ---- 25-tap weighted gather over 21 channels, fp16 LDS, fp32 accumulate ----
    float acc[NCH];
#pragma unroll
    for (int c = 0; c < NCH; c++) acc[c] = 0.f;

    const int base = ty * HX + tx;
#pragma unroll
    for (int dy = 0; dy < KS; dy++) {
#pragma unroll
        for (int dx = 0; dx < KS; dx++) {
            const float w = wcr[dy * KS + dx];
            const f16* tp = &tileH[base + dy * HX + dx][0];
            half8 v0 = *(const half8*)(tp);
            half8 v1 = *(const half8*)(tp + 8);
            half8 v2 = *(const half8*)(tp + 16);
#pragma unroll
            for (int k = 0; k < 8; k++) acc[k]      = fmaf((float)v0[k], w, acc[k]);
#pragma unroll
            for (int k = 0; k < 8; k++) acc[8 + k]  = fmaf((float)v1[k], w, acc[8 + k]);
#pragma unroll
            for (int k = 0; k < 5; k++) acc[16 + k] = fmaf((float)v2[k], w, acc[16 + k]);
        }
    }

    // ---- logits + softmax (registers), unary is interleaved fp32 ----
    const float* ub = uint_ + ((size_t)b * plane + (size_t)y * WW + x) * CPAD;
    float l[NCH];
#pragma unroll
    for (int c = 0; c < NCH; c++) l[c] = ub[c] - acc[c];
    float m = l[0];
#pragma unroll
    for (int c = 1; c < NCH; c++) m = fmaxf(m, l[c]);
    float s = 0.f;
#pragma unroll
    for (int c = 0; c < NCH; c++) { l[c] = expf(l[c] - m); s += l[c]; }
    float is = 1.0f / s;
#pragma unroll
    for (int c = 0; c < NCH; c++) l[c] *= is;

    if (FINAL) {
        float* qo = (float*)qout + (size_t)b * NCH * plane + (size_t)y * WW + x;
#pragma unroll
        for (int c = 0; c < NCH; c++) qo[c * plane] = l[c];
    } else {
        half8* qo = (half8*)((f16*)qout + ((size_t)b * plane + (size_t)y * WW + x) * CPAD);
        float lp[CPAD];
#pragma unroll
        for (int c = 0; c < NCH; c++) lp[c] = l[c];
        lp[21] = 0.f; lp[22] = 0.f; lp[23] = 0.f;
#pragma unroll
        for (int g = 0; g < 3; g++) {
            half8 v;
#pragma unroll
            for (int k = 0; k < 8; k++) v[k] = (f16)lp[g * 8 + k];
            qo[g] = v;
        }
    }
}

extern "C" void kernel_launch(void* const* d_in, const int* in_sizes, int n_in,
                              void* d_out, int out_size, void* d_ws, size_t ws_size,
                              hipStream_t stream) {
    const float* unary = (const float*)d_in[0];   // B,21,512,512
    const float* image = (const float*)d_in[1];   // B,3,512,512
    const float* edges = (const float*)d_in[2];   // B,512,512
    float* out = (float*)d_out;                   // B,21,512,512 fp32

    const size_t plane = (size_t)HH * WW;
    char* ws = (char*)d_ws;
    half2v* wc2 = (half2v*)ws;                                   // B*13*plane half2  = 27.3 MB
    char* p1 = ws + sizeof(half2v) * BATCH * NPAIR * plane;
    float* uint_ = (float*)p1;                                   // B*plane*24 fp32   = 50.3 MB
    char* p2 = p1 + sizeof(float) * BATCH * plane * CPAD;
    f16* qA = (f16*)p2;                                          // B*plane*24 fp16   = 25.2 MB
    f16* qB = qA + (size_t)BATCH * plane * CPAD;                 // 25.2 MB   (total ~128 MB)

    const int npix = BATCH * HH * WW;
    weights_kernel<<<(npix + 255) / 256, 256, 0, stream>>>(image, edges, wc2);
    init_kernel<<<(npix + 255) / 256, 256, 0, stream>>>(unary, qA, uint_);

    dim3 grid(WW / TX, HH / TY, BATCH);
    dim3 block(TX, TY, 1);
    f16* qa = qA;
    f16* qb = qB;
    for (int it = 0; it < NUM_ITERS - 1; it++) {
        crf_iter_kernel<false><<<grid, block, 0, stream>>>(qa, uint_, wc2, (void*)qb);
        f16* t = qa; qa = qb; qb = t;
    }
    crf_iter_kernel<true><<<grid, block, 0, stream>>>(qa, uint_, wc2, (void*)out);
}

// Round 4
// 338.858 us; speedup vs baseline: 1.2088x; 1.2088x over previous
//
#include <hip/hip_runtime.h>
#include <math.h>

#define BATCH 2
#define NCH 21
#define CPAD 24            // channels padded to 24 (48 B fp16 per pixel)
#define HH 512
#define WW 512
#define KS 5
#define RAD 2
#define NTAPS 25
#define NPAIR 13           // 25 taps packed as 13 half2 pairs (last hi = 0)
#define NUM_ITERS 10

// tile geometry (shared by weights + iter kernels)
#define TX 32
#define TY 8
#define HX (TX + 2*RAD)    // 36
#define HY (TY + 2*RAD)    // 12
#define HPX (HX * HY)      // 432 halo pixels

typedef _Float16 f16;
typedef _Float16 half8 __attribute__((ext_vector_type(8)));
typedef _Float16 half2v __attribute__((ext_vector_type(2)));

__device__ __forceinline__ int refl(int i, int n) {
    if (i < 0) i = -i;
    if (i >= n) i = 2*n - 2 - i;
    return i;
}

// ---------------- Kernel A: combined normalized weights, LDS-tiled guide ----------------
// w[tap] = G2d_norm[tap] + w_rgb[tap]/sum(w_rgb) + w_edge[tap]/sum(w_edge)
// layout: wc2[b][pair][y][x] = half2(w[2*pair], w[2*pair+1]), w[25]=0
__global__ __launch_bounds__(256) void weights_kernel(const float* __restrict__ image,
                                                      const float* __restrict__ edges,
                                                      half2v* __restrict__ wc2) {
    __shared__ float sr_[HY][HX];
    __shared__ float sg_[HY][HX];
    __shared__ float sb_[HY][HX];
    __shared__ float se_[HY][HX];   // 4 * 1728 B = 6912 B

    const int tx = threadIdx.x;      // 0..31
    const int ty = threadIdx.y;      // 0..7
    const int tid = ty * TX + tx;
    const int x0 = blockIdx.x * TX;
    const int y0 = blockIdx.y * TY;
    const int b = blockIdx.z;
    const int x = x0 + tx;
    const int y = y0 + ty;
    const size_t plane = (size_t)HH * WW;
    const float* img = image + (size_t)b * 3 * plane;
    const float* edg = edges + (size_t)b * plane;

    for (int i = tid; i < HPX; i += TX * TY) {
        int ly = i / HX, lx = i - ly * HX;
        int gy = refl(y0 + ly - RAD, HH);
        int gx = refl(x0 + lx - RAD, WW);
        int g = gy * WW + gx;
        sr_[ly][lx] = img[g];
        sg_[ly][lx] = img[plane + g];
        sb_[ly][lx] = img[2 * plane + g];
        se_[ly][lx] = edg[g];
    }
    __syncthreads();

    // spatial gaussian (sigma_space=5; normalization cancels) and blur gaussian (sigma=0.5)
    float gs[3];
    gs[0] = 1.0f; gs[1] = __expf(-1.0f / 50.0f); gs[2] = __expf(-4.0f / 50.0f);
    float gb[3];
    gb[0] = 1.0f; gb[1] = __expf(-2.0f); gb[2] = __expf(-8.0f);
    float gbs = gb[0] + 2.0f * (gb[1] + gb[2]);
    gb[0] /= gbs; gb[1] /= gbs; gb[2] /= gbs;

    const float r0 = sr_[ty + RAD][tx + RAD];
    const float g0 = sg_[ty + RAD][tx + RAD];
    const float b0 = sb_[ty + RAD][tx + RAD];
    const float e0 = se_[ty + RAD][tx + RAD];

    float wr[NTAPS], we[NTAPS];
    float sr = 0.f, se = 0.f;
#pragma unroll
    for (int dy = 0; dy < KS; dy++) {
#pragma unroll
        for (int dx = 0; dx < KS; dx++) {
            float sp = gs[abs(dy - RAD)] * gs[abs(dx - RAD)];
            float d = fabsf(sr_[ty + dy][tx + dx] - r0)
                    + fabsf(sg_[ty + dy][tx + dx] - g0)
                    + fabsf(sb_[ty + dy][tx + dx] - b0);
            float w1 = sp * __expf(-2.0f * d * d);    // inv2sc2 = -0.5/0.25
            float de = fabsf(se_[ty + dy][tx + dx] - e0);
            float w2 = sp * __expf(-2.0f * de * de);
            wr[dy * KS + dx] = w1;
            we[dy * KS + dx] = w2;
            sr += w1;
            se += w2;
        }
    }
    float isr = 1.0f / sr, ise = 1.0f / se;
    float wt[NTAPS + 1];
#pragma unroll
    for (int t = 0; t < NTAPS; t++) {
        int dy = t / KS, dx = t % KS;
        float g2 = gb[abs(dy - RAD)] * gb[abs(dx - RAD)];
        wt[t] = g2 + wr[t] * isr + we[t] * ise;
    }
    wt[NTAPS] = 0.f;
#pragma unroll
    for (int p = 0; p < NPAIR; p++) {
        half2v h;
        h[0] = (f16)wt[2 * p];
        h[1] = (f16)wt[2 * p + 1];
        wc2[((size_t)b * NPAIR + p) * plane + (size_t)y * WW + x] = h;
    }
}

// ---------------- Kernel B: initial softmax -> interleaved fp16 q + interleaved fp16 unary ----------------
__global__ void init_kernel(const float* __restrict__ unary,
                            f16* __restrict__ q,
                            f16* __restrict__ u16) {
    int idx = blockIdx.x * blockDim.x + threadIdx.x;
    if (idx >= BATCH * HH * WW) return;
    int p = idx % (HH * WW);
    int b = idx / (HH * WW);
    const size_t plane = (size_t)HH * WW;
    const float* u = unary + (size_t)b * NCH * plane + p;
    float l[CPAD];
    float m = -1e30f;
#pragma unroll
    for (int c = 0; c < NCH; c++) { l[c] = u[c * plane]; m = fmaxf(m, l[c]); }
    l[21] = 0.f; l[22] = 0.f; l[23] = 0.f;

    // interleaved fp16 unary
    half8* uo = (half8*)(u16 + ((size_t)b * plane + p) * CPAD);
#pragma unroll
    for (int g = 0; g < 3; g++) {
        half8 v;
#pragma unroll
        for (int k = 0; k < 8; k++) v[k] = (f16)l[g * 8 + k];
        uo[g] = v;
    }

    float s = 0.f;
    float e[CPAD];
#pragma unroll
    for (int c = 0; c < NCH; c++) { e[c] = __expf(l[c] - m); s += e[c]; }
    float is = 1.0f / s;
    e[21] = 0.f; e[22] = 0.f; e[23] = 0.f;
    half8* qo = (half8*)(q + ((size_t)b * plane + p) * CPAD);
#pragma unroll
    for (int g = 0; g < 3; g++) {
        half8 v;
#pragma unroll
        for (int k = 0; k < 8; k++) v[k] = (f16)(e[g * 8 + k] * is);
        qo[g] = v;
    }
}

// ---------------- Kernel C: one fused CRF iteration ----------------
// new_q = softmax(unary - f),  f_c = sum_tap w[tap] * q[c][nbr(tap)]
template <bool FINAL>
__global__ __launch_bounds__(256, 4) void crf_iter_kernel(const f16* __restrict__ qin,
                                                          const f16* __restrict__ u16,
                                                          const half2v* __restrict__ wc2,
                                                          void* __restrict__ qout) {
    // fp16 halo tile, interleaved: tileH[px][24 halfs] = 48 B/px, 20736 B total
    __shared__ __align__(16) f16 tileH[HPX][CPAD];

    const int tx = threadIdx.x;      // 0..31
    const int ty = threadIdx.y;      // 0..7
    const int tid = ty * TX + tx;
    const int x0 = blockIdx.x * TX;
    const int y0 = blockIdx.y * TY;
    const int b = blockIdx.z;
    const int x = x0 + tx;
    const int y = y0 + ty;
    const size_t plane = (size_t)HH * WW;

    // ---- stage 12x36 halo, fp16 global -> fp16 LDS, no conversion ----
    const f16* qb = qin + (size_t)b * plane * CPAD;
    for (int idx = tid; idx < HPX * 3; idx += TX * TY) {
        int px = idx / 3, h4 = idx - px * 3;        // h4-fastest: contiguous 16B global chunks
        int ly = px / HX, lx = px - ly * HX;
        int gy = refl(y0 + ly - RAD, HH);
        int gx = refl(x0 + lx - RAD, WW);
        half8 v = *(const half8*)(qb + ((size_t)gy * WW + gx) * CPAD + h4 * 8);
        *(half8*)&tileH[px][h4 * 8] = v;
    }

    // per-pixel combined weights, half2 pairs -> fp32 registers
    float wcr[NTAPS + 1];
    {
        const half2v* wp = wc2 + (size_t)b * NPAIR * plane + (size_t)y * WW + x;
#pragma unroll
        for (int p = 0; p < NPAIR; p++) {
            half2v h = wp[p * plane];
            wcr[2 * p] = (float)h[0];
            wcr[2 * p + 1] = (float)h[1];
        }
    }

    __syncthreads();

    // ---- 25-tap weighted gather over 21 channels, fp16 LDS, fp32 accumulate ----
    float acc[NCH];
#pragma unroll
    for (int c = 0; c < NCH; c++) acc[c] = 0.f;

    const int base = ty * HX + tx;
#pragma unroll
    for (int dy = 0; dy < KS; dy++) {
#pragma unroll
        for (int dx = 0; dx < KS; dx++) {
            const float w = wcr[dy * KS + dx];
            const f16* tp = &tileH[base + dy * HX + dx][0];
            half8 v0 = *(const half8*)(tp);
            half8 v1 = *(const half8*)(tp + 8);
            half8 v2 = *(const half8*)(tp + 16);
#pragma unroll
            for (int k = 0; k < 8; k++) acc[k]      = fmaf((float)v0[k], w, acc[k]);
#pragma unroll
            for (int k = 0; k < 8; k++) acc[8 + k]  = fmaf((float)v1[k], w, acc[8 + k]);
#pragma unroll
            for (int k = 0; k < 5; k++) acc[16 + k] = fmaf((float)v2[k], w, acc[16 + k]);
        }
    }

    // ---- logits + softmax (registers), unary interleaved fp16 ----
    const f16* ub = u16 + ((size_t)b * plane + (size_t)y * WW + x) * CPAD;
    half8 u0 = *(const half8*)(ub);
    half8 u1 = *(const half8*)(ub + 8);
    half8 u2 = *(const half8*)(ub + 16);
    float l[NCH];
#pragma unroll
    for (int k = 0; k < 8; k++) l[k] = (float)u0[k] - acc[k];
#pragma unroll
    for (int k = 0; k < 8; k++) l[8 + k] = (float)u1[k] - acc[8 + k];
#pragma unroll
    for (int k = 0; k < 5; k++) l[16 + k] = (float)u2[k] - acc[16 + k];

    float m = l[0];
#pragma unroll
    for (int c = 1; c < NCH; c++) m = fmaxf(m, l[c]);
    float s = 0.f;
#pragma unroll
    for (int c = 0; c < NCH; c++) { l[c] = __expf(l[c] - m); s += l[c]; }
    float is = 1.0f / s;
#pragma unroll
    for (int c = 0; c < NCH; c++) l[c] *= is;

    if (FINAL) {
        float* qo = (float*)qout + (size_t)b * NCH * plane + (size_t)y * WW + x;
#pragma unroll
        for (int c = 0; c < NCH; c++) qo[c * plane] = l[c];
    } else {
        half8* qo = (half8*)((f16*)qout + ((size_t)b * plane + (size_t)y * WW + x) * CPAD);
        float lp[CPAD];
#pragma unroll
        for (int c = 0; c < NCH; c++) lp[c] = l[c];
        lp[21] = 0.f; lp[22] = 0.f; lp[23] = 0.f;
#pragma unroll
        for (int g = 0; g < 3; g++) {
            half8 v;
#pragma unroll
            for (int k = 0; k < 8; k++) v[k] = (f16)lp[g * 8 + k];
            qo[g] = v;
        }
    }
}

extern "C" void kernel_launch(void* const* d_in, const int* in_sizes, int n_in,
                              void* d_out, int out_size, void* d_ws, size_t ws_size,
                              hipStream_t stream) {
    const float* unary = (const float*)d_in[0];   // B,21,512,512
    const float* image = (const float*)d_in[1];   // B,3,512,512
    const float* edges = (const float*)d_in[2];   // B,512,512
    float* out = (float*)d_out;                   // B,21,512,512 fp32

    const size_t plane = (size_t)HH * WW;
    char* ws = (char*)d_ws;
    half2v* wc2 = (half2v*)ws;                                   // B*13*plane half2  = 27.3 MB
    char* p1 = ws + sizeof(half2v) * BATCH * NPAIR * plane;
    f16* u16 = (f16*)p1;                                         // B*plane*24 fp16   = 25.2 MB
    char* p2 = p1 + sizeof(f16) * BATCH * plane * CPAD;
    f16* qA = (f16*)p2;                                          // 25.2 MB
    f16* qB = qA + (size_t)BATCH * plane * CPAD;                 // 25.2 MB  (total ~103 MB)

    const int npix = BATCH * HH * WW;
    dim3 grid(WW / TX, HH / TY, BATCH);
    dim3 block(TX, TY, 1);

    weights_kernel<<<grid, block, 0, stream>>>(image, edges, wc2);
    init_kernel<<<(npix + 255) / 256, 256, 0, stream>>>(unary, qA, u16);

    f16* qa = qA;
    f16* qb = qB;
    for (int it = 0; it < NUM_ITERS - 1; it++) {
        crf_iter_kernel<false><<<grid, block, 0, stream>>>(qa, u16, wc2, (void*)qb);
        f16* t = qa; qa = qb; qb = t;
    }
    crf_iter_kernel<true><<<grid, block, 0, stream>>>(qa, u16, wc2, (void*)out);
}

// Round 5
// 317.307 us; speedup vs baseline: 1.2909x; 1.0679x over previous
//
#include <hip/hip_runtime.h>
#include <math.h>

#define BATCH 2
#define NCH 21
#define CPAD 24            // channels padded to 24 (48 B fp16 per pixel)
#define HH 512
#define WW 512
#define KS 5
#define RAD 2
#define NTAPS 25
#define NPAIR 13           // 25 taps packed as 13 half2 pairs (last hi = 0)
#define NUM_ITERS 10

// tile geometry
#define TX 32
#define TY 8
#define HX (TX + 2*RAD)    // 36
#define HY (TY + 2*RAD)    // 12
#define HPX (HX * HY)      // 432 halo pixels
#define NCHUNK (HPX * 3)   // 1296 16-byte chunks to stage

typedef _Float16 f16;
typedef _Float16 half8 __attribute__((ext_vector_type(8)));
typedef _Float16 half2v __attribute__((ext_vector_type(2)));

__device__ __forceinline__ int refl(int i, int n) {
    if (i < 0) i = -i;
    if (i >= n) i = 2*n - 2 - i;
    return i;
}

// ---------------- Kernel A: combined normalized weights, LDS-tiled guide ----------------
__global__ __launch_bounds__(256) void weights_kernel(const float* __restrict__ image,
                                                      const float* __restrict__ edges,
                                                      half2v* __restrict__ wc2) {
    __shared__ float sr_[HY][HX];
    __shared__ float sg_[HY][HX];
    __shared__ float sb_[HY][HX];
    __shared__ float se_[HY][HX];

    const int tx = threadIdx.x;
    const int ty = threadIdx.y;
    const int tid = ty * TX + tx;
    const int x0 = blockIdx.x * TX;
    const int y0 = blockIdx.y * TY;
    const int b = blockIdx.z;
    const int x = x0 + tx;
    const int y = y0 + ty;
    const size_t plane = (size_t)HH * WW;
    const float* img = image + (size_t)b * 3 * plane;
    const float* edg = edges + (size_t)b * plane;

    for (int i = tid; i < HPX; i += TX * TY) {
        int ly = i / HX, lx = i - ly * HX;
        int gy = refl(y0 + ly - RAD, HH);
        int gx = refl(x0 + lx - RAD, WW);
        int g = gy * WW + gx;
        sr_[ly][lx] = img[g];
        sg_[ly][lx] = img[plane + g];
        sb_[ly][lx] = img[2 * plane + g];
        se_[ly][lx] = edg[g];
    }
    __syncthreads();

    float gs[3];
    gs[0] = 1.0f; gs[1] = __expf(-1.0f / 50.0f); gs[2] = __expf(-4.0f / 50.0f);
    float gb[3];
    gb[0] = 1.0f; gb[1] = __expf(-2.0f); gb[2] = __expf(-8.0f);
    float gbs = gb[0] + 2.0f * (gb[1] + gb[2]);
    gb[0] /= gbs; gb[1] /= gbs; gb[2] /= gbs;

    const float r0 = sr_[ty + RAD][tx + RAD];
    const float g0 = sg_[ty + RAD][tx + RAD];
    const float b0 = sb_[ty + RAD][tx + RAD];
    const float e0 = se_[ty + RAD][tx + RAD];

    float wr[NTAPS], we[NTAPS];
    float sr = 0.f, se = 0.f;
#pragma unroll
    for (int dy = 0; dy < KS; dy++) {
#pragma unroll
        for (int dx = 0; dx < KS; dx++) {
            float sp = gs[abs(dy - RAD)] * gs[abs(dx - RAD)];
            float d = fabsf(sr_[ty + dy][tx + dx] - r0)
                    + fabsf(sg_[ty + dy][tx + dx] - g0)
                    + fabsf(sb_[ty + dy][tx + dx] - b0);
            float w1 = sp * __expf(-2.0f * d * d);
            float de = fabsf(se_[ty + dy][tx + dx] - e0);
            float w2 = sp * __expf(-2.0f * de * de);
            wr[dy * KS + dx] = w1;
            we[dy * KS + dx] = w2;
            sr += w1;
            se += w2;
        }
    }
    float isr = 1.0f / sr, ise = 1.0f / se;
    float wt[NTAPS + 1];
#pragma unroll
    for (int t = 0; t < NTAPS; t++) {
        int dy = t / KS, dx = t % KS;
        float g2 = gb[abs(dy - RAD)] * gb[abs(dx - RAD)];
        wt[t] = g2 + wr[t] * isr + we[t] * ise;
    }
    wt[NTAPS] = 0.f;
#pragma unroll
    for (int p = 0; p < NPAIR; p++) {
        half2v h;
        h[0] = (f16)wt[2 * p];
        h[1] = (f16)wt[2 * p + 1];
        wc2[((size_t)b * NPAIR + p) * plane + (size_t)y * WW + x] = h;
    }
}

// ---------------- Kernel B: initial softmax -> interleaved fp16 q + fp16 unary ----------------
__global__ void init_kernel(const float* __restrict__ unary,
                            f16* __restrict__ q,
                            f16* __restrict__ u16) {
    int idx = blockIdx.x * blockDim.x + threadIdx.x;
    if (idx >= BATCH * HH * WW) return;
    int p = idx % (HH * WW);
    int b = idx / (HH * WW);
    const size_t plane = (size_t)HH * WW;
    const float* u = unary + (size_t)b * NCH * plane + p;
    float l[CPAD];
    float m = -1e30f;
#pragma unroll
    for (int c = 0; c < NCH; c++) { l[c] = u[c * plane]; m = fmaxf(m, l[c]); }
    l[21] = 0.f; l[22] = 0.f; l[23] = 0.f;

    half8* uo = (half8*)(u16 + ((size_t)b * plane + p) * CPAD);
#pragma unroll
    for (int g = 0; g < 3; g++) {
        half8 v;
#pragma unroll
        for (int k = 0; k < 8; k++) v[k] = (f16)l[g * 8 + k];
        uo[g] = v;
    }

    float s = 0.f;
    float e[CPAD];
#pragma unroll
    for (int c = 0; c < NCH; c++) { e[c] = __expf(l[c] - m); s += e[c]; }
    float is = 1.0f / s;
    e[21] = 0.f; e[22] = 0.f; e[23] = 0.f;
    half8* qo = (half8*)(q + ((size_t)b * plane + p) * CPAD);
#pragma unroll
    for (int g = 0; g < 3; g++) {
        half8 v;
#pragma unroll
        for (int k = 0; k < 8; k++) v[k] = (f16)(e[g * 8 + k] * is);
        qo[g] = v;
    }
}

// ---------------- Kernel C: one fused CRF iteration ----------------
// 1-D grid of 2048 blocks, XCD band swizzle; async direct-to-LDS staging.
template <bool FINAL>
__global__ __launch_bounds__(256, 5) void crf_iter_kernel(const f16* __restrict__ qin,
                                                          const f16* __restrict__ u16,
                                                          const half2v* __restrict__ wc2,
                                                          void* __restrict__ qout) {
    __shared__ __align__(16) f16 tileH[HPX][CPAD];   // 20736 B

    const int tid = threadIdx.x;          // 0..255
    const int tx = tid & (TX - 1);        // 0..31
    const int ty = tid >> 5;              // 0..7

    // XCD band swizzle: XCD (flat%8) owns one horizontal band of 8 tile-rows
    const int flat = blockIdx.x;          // 0..2047
    const int band = flat & 7;
    const int within = flat >> 3;         // 0..255
    const int b = within >> 7;            // batch
    const int r = within & 127;
    const int x0 = (r & 15) * TX;
    const int y0 = (band * 8 + (r >> 4)) * TY;
    const int x = x0 + tx;
    const int y = y0 + ty;
    const size_t plane = (size_t)HH * WW;

    // ---- async stage 12x36 halo (fp16, interleaved) straight into LDS ----
    const f16* qb = qin + (size_t)b * plane * CPAD;
    f16* lbase = &tileH[0][0];
#pragma unroll
    for (int rnd = 0; rnd < 5; rnd++) {
        int idx = tid + rnd * 256;
        int px = idx / 3, h4 = idx - px * 3;
        int ly = px / HX, lx = px - ly * HX;
        int gy = refl(y0 + ly - RAD, HH);
        int gx = refl(x0 + lx - RAD, WW);
        const f16* g = qb + ((size_t)(gy * WW + gx)) * CPAD + h4 * 8;
        __builtin_amdgcn_global_load_lds(
            (const __attribute__((address_space(1))) void*)g,
            (__attribute__((address_space(3))) void*)(lbase + (size_t)idx * 8),
            16, 0, 0);
    }
    if (tid < NCHUNK - 5 * 256) {         // 16 remainder chunks
        int idx = tid + 5 * 256;
        int px = idx / 3, h4 = idx - px * 3;
        int ly = px / HX, lx = px - ly * HX;
        int gy = refl(y0 + ly - RAD, HH);
        int gx = refl(x0 + lx - RAD, WW);
        const f16* g = qb + ((size_t)(gy * WW + gx)) * CPAD + h4 * 8;
        __builtin_amdgcn_global_load_lds(
            (const __attribute__((address_space(1))) void*)g,
            (__attribute__((address_space(3))) void*)(lbase + (size_t)idx * 8),
            16, 0, 0);
    }

    // ---- prefetch per-pixel weights + unary while staging is in flight ----
    float wcr[NTAPS + 1];
    {
        const half2v* wp = wc2 + (size_t)b * NPAIR * plane + (size_t)y * WW + x;
#pragma unroll
        for (int p = 0; p < NPAIR; p++) {
            half2v h = wp[p * plane];
            wcr[2 * p] = (float)h[0];
            wcr[2 * p + 1] = (float)h[1];
        }
    }
    const f16* ub = u16 + ((size_t)b * plane + (size_t)y * WW + x) * CPAD;
    half8 u0 = *(const half8*)(ub);
    half8 u1 = *(const half8*)(ub + 8);
    half8 u2 = *(const half8*)(ub + 16);

    __syncthreads();   // drains the LDS-DMA (vmcnt 0) + joins block

    // ---- 25-tap weighted gather over 21 channels, fp16 LDS, fp32 accumulate ----
    float acc[NCH];
#pragma unroll
    for (int c = 0; c < NCH; c++) acc[c] = 0.f;

    const int base = ty * HX + tx;
#pragma unroll
    for (int dy = 0; dy < KS; dy++) {
#pragma unroll
        for (int dx = 0; dx < KS; dx++) {
            const float w = wcr[dy * KS + dx];
            const f16* tp = &tileH[base + dy * HX + dx][0];
            half8 v0 = *(const half8*)(tp);
            half8 v1 = *(const half8*)(tp + 8);
            half8 v2 = *(const half8*)(tp + 16);
#pragma unroll
            for (int k = 0; k < 8; k++) acc[k]      = fmaf((float)v0[k], w, acc[k]);
#pragma unroll
            for (int k = 0; k < 8; k++) acc[8 + k]  = fmaf((float)v1[k], w, acc[8 + k]);
#pragma unroll
            for (int k = 0; k < 5; k++) acc[16 + k] = fmaf((float)v2[k], w, acc[16 + k]);
        }
    }

    // ---- logits + softmax (registers) ----
    float l[NCH];
#pragma unroll
    for (int k = 0; k < 8; k++) l[k] = (float)u0[k] - acc[k];
#pragma unroll
    for (int k = 0; k < 8; k++) l[8 + k] = (float)u1[k] - acc[8 + k];
#pragma unroll
    for (int k = 0; k < 5; k++) l[16 + k] = (float)u2[k] - acc[16 + k];

    float m = l[0];
#pragma unroll
    for (int c = 1; c < NCH; c++) m = fmaxf(m, l[c]);
    float s = 0.f;
#pragma unroll
    for (int c = 0; c < NCH; c++) { l[c] = __expf(l[c] - m); s += l[c]; }
    float is = 1.0f / s;
#pragma unroll
    for (int c = 0; c < NCH; c++) l[c] *= is;

    if (FINAL) {
        float* qo = (float*)qout + (size_t)b * NCH * plane + (size_t)y * WW + x;
#pragma unroll
        for (int c = 0; c < NCH; c++) qo[c * plane] = l[c];
    } else {
        half8* qo = (half8*)((f16*)qout + ((size_t)b * plane + (size_t)y * WW + x) * CPAD);
        float lp[CPAD];
#pragma unroll
        for (int c = 0; c < NCH; c++) lp[c] = l[c];
        lp[21] = 0.f; lp[22] = 0.f; lp[23] = 0.f;
#pragma unroll
        for (int g = 0; g < 3; g++) {
            half8 v;
#pragma unroll
            for (int k = 0; k < 8; k++) v[k] = (f16)lp[g * 8 + k];
            qo[g] = v;
        }
    }
}

extern "C" void kernel_launch(void* const* d_in, const int* in_sizes, int n_in,
                              void* d_out, int out_size, void* d_ws, size_t ws_size,
                              hipStream_t stream) {
    const float* unary = (const float*)d_in[0];   // B,21,512,512
    const float* image = (const float*)d_in[1];   // B,3,512,512
    const float* edges = (const float*)d_in[2];   // B,512,512
    float* out = (float*)d_out;                   // B,21,512,512 fp32

    const size_t plane = (size_t)HH * WW;
    char* ws = (char*)d_ws;
    half2v* wc2 = (half2v*)ws;                                   // B*13*plane half2  = 27.3 MB
    char* p1 = ws + sizeof(half2v) * BATCH * NPAIR * plane;
    f16* u16 = (f16*)p1;                                         // B*plane*24 fp16   = 25.2 MB
    char* p2 = p1 + sizeof(f16) * BATCH * plane * CPAD;
    f16* qA = (f16*)p2;                                          // 25.2 MB
    f16* qB = qA + (size_t)BATCH * plane * CPAD;                 // 25.2 MB  (total ~103 MB)

    const int npix = BATCH * HH * WW;
    dim3 gridW(WW / TX, HH / TY, BATCH);
    dim3 blockW(TX, TY, 1);
    weights_kernel<<<gridW, blockW, 0, stream>>>(image, edges, wc2);
    init_kernel<<<(npix + 255) / 256, 256, 0, stream>>>(unary, qA, u16);

    const int nblk = (WW / TX) * (HH / TY) * BATCH;   // 2048
    f16* qa = qA;
    f16* qb = qB;
    for (int it = 0; it < NUM_ITERS - 1; it++) {
        crf_iter_kernel<false><<<nblk, 256, 0, stream>>>(qa, u16, wc2, (void*)qb);
        f16* t = qa; qa = qb; qb = t;
    }
    crf_iter_kernel<true><<<nblk, 256, 0, stream>>>(qa, u16, wc2, (void*)out);
}